// Round 5
// baseline (949.666 us; speedup 1.0000x reference)
//
#include <hip/hip_runtime.h>

typedef unsigned int uint32;

#define NSB 256          // scatter/hist blocks
#define MAXNB 1280       // LDS capacity for bucket counters (NB = ceil(num_owned/64) <= 1280)

__device__ __forceinline__ unsigned short f2bf(float f) {
  uint32 b = __float_as_uint(f);
  uint32 r = (b + 0x7fffu + ((b >> 16) & 1u)) >> 16;   // round-to-nearest-even
  return (unsigned short)r;
}
__device__ __forceinline__ float bf2f(unsigned short u) {
  return __uint_as_float(((uint32)u) << 16);
}

// ---------------- GEMM with deg scaling: h[r][c] = dis[r] * sum_k x[r][k]*w[k][c]
// h stored bf16. block 256; tile 64 rows x 128 cols; BK=32; thread: 8 rows x 4 cols.
__global__ __launch_bounds__(256)
void gemm_scale_kernel(const float* __restrict__ x, const float* __restrict__ w,
                       const float* __restrict__ dis, unsigned short* __restrict__ hb, int NL) {
  const int IC = 128, OC = 128, BK = 32;
  __shared__ float xs[64][BK + 4];
  __shared__ float ws[BK][OC];
  const int tid = threadIdx.x;
  const int tx = tid & 31;
  const int ty = tid >> 5;
  const int row0 = blockIdx.x * 64;
  float acc[8][4] = {};

  for (int kc = 0; kc < IC; kc += BK) {
#pragma unroll
    for (int i = 0; i < 2; ++i) {
      int idx = i * 256 + tid;
      int r = idx >> 3, c4 = idx & 7;
      float4 v = make_float4(0.f, 0.f, 0.f, 0.f);
      int gr = row0 + r;
      if (gr < NL) v = *(const float4*)&x[(size_t)gr * IC + kc + c4 * 4];
      *(float4*)&xs[r][c4 * 4] = v;
    }
#pragma unroll
    for (int i = 0; i < 4; ++i) {
      int idx = i * 256 + tid;
      int r = idx >> 5, c4 = idx & 31;
      *(float4*)&ws[r][c4 * 4] = *(const float4*)&w[(size_t)(kc + r) * OC + c4 * 4];
    }
    __syncthreads();
#pragma unroll
    for (int k = 0; k < BK; ++k) {
      float4 wv = *(const float4*)&ws[k][tx * 4];
#pragma unroll
      for (int i = 0; i < 8; ++i) {
        float xv = xs[ty * 8 + i][k];
        acc[i][0] += xv * wv.x;
        acc[i][1] += xv * wv.y;
        acc[i][2] += xv * wv.z;
        acc[i][3] += xv * wv.w;
      }
    }
    __syncthreads();
  }
#pragma unroll
  for (int i = 0; i < 8; ++i) {
    int r = row0 + ty * 8 + i;
    if (r < NL) {
      float d = dis[r];
      ushort4 o;
      o.x = f2bf(acc[i][0] * d);
      o.y = f2bf(acc[i][1] * d);
      o.z = f2bf(acc[i][2] * d);
      o.w = f2bf(acc[i][3] * d);
      *(ushort4*)&hb[(size_t)r * OC + tx * 4] = o;
    }
  }
}

// ---------------- per-block bucket histogram (bucket = dst>>6), LDS-privatized
__global__ __launch_bounds__(256)
void bhist_kernel(const int* __restrict__ row, int* __restrict__ bcnt,
                  int NE, int num_owned, int NB, int chunk) {
  __shared__ int h[MAXNB];
  const int tid = threadIdx.x;
  const int blk = blockIdx.x;
  for (int b = tid; b < NB; b += 256) h[b] = 0;
  __syncthreads();
  int s = blk * chunk;
  int e = min(s + chunk, NE);
  for (int i = s + tid; i < e; i += 256) {
    int r = row[i];
    if (r < num_owned) atomicAdd(&h[r >> 6], 1);
  }
  __syncthreads();
  // column blk of the [NB][NSB] count matrix
  for (int b = tid; b < NB; b += 256) bcnt[b * NSB + blk] = h[b];
}

// ---------------- 2-level exclusive scan over n = NB*NSB counts
__global__ __launch_bounds__(256)
void scan_block_kernel(const int* __restrict__ counts, int* __restrict__ offsets,
                       int* __restrict__ bsum, int n) {
  __shared__ int lds[256];
  int tid = threadIdx.x;
  int i = blockIdx.x * 256 + tid;
  int v = (i < n) ? counts[i] : 0;
  lds[tid] = v;
  __syncthreads();
#pragma unroll
  for (int off = 1; off < 256; off <<= 1) {
    int t = (tid >= off) ? lds[tid - off] : 0;
    __syncthreads();
    lds[tid] += t;
    __syncthreads();
  }
  if (i < n) offsets[i] = lds[tid] - v;
  if (tid == 255) bsum[blockIdx.x] = lds[255];
}

// single-block looping scan over nb block sums (nb can exceed 512)
__global__ __launch_bounds__(512)
void scan_top_kernel(const int* __restrict__ bsum, int* __restrict__ bsum2, int nb) {
  __shared__ int lds[512];
  __shared__ int carry;
  int tid = threadIdx.x;
  if (tid == 0) carry = 0;
  __syncthreads();
  for (int base = 0; base < nb; base += 512) {
    int idx = base + tid;
    int v = (idx < nb) ? bsum[idx] : 0;
    lds[tid] = v;
    __syncthreads();
    for (int off = 1; off < 512; off <<= 1) {
      int t = (tid >= off) ? lds[tid - off] : 0;
      __syncthreads();
      lds[tid] += t;
      __syncthreads();
    }
    if (idx < nb) bsum2[idx] = carry + lds[tid] - v;   // exclusive
    __syncthreads();
    if (tid == 0) carry += lds[511];
    __syncthreads();
  }
}

// add block offsets; write grand total at offsets[n]
__global__ __launch_bounds__(256)
void add_off_kernel(int* __restrict__ offsets, const int* __restrict__ bsum2,
                    const int* __restrict__ counts, int n) {
  int i = blockIdx.x * 256 + threadIdx.x;
  if (i < n) {
    int o = offsets[i] + bsum2[blockIdx.x];
    offsets[i] = o;
    if (i == n - 1) offsets[n] = o + counts[i];
  }
}

// ---------------- scatter edges into bucket-ordered packed array (block-private runs)
__global__ __launch_bounds__(256)
void scatter_kernel(const int* __restrict__ row, const int* __restrict__ col,
                    const int* __restrict__ bstart, uint32* __restrict__ pairs,
                    int NE, int num_owned, int NB, int chunk) {
  __shared__ int cur[MAXNB];
  const int tid = threadIdx.x;
  const int blk = blockIdx.x;
  for (int b = tid; b < NB; b += 256) cur[b] = bstart[b * NSB + blk];
  __syncthreads();
  int s = blk * chunk;
  int e = min(s + chunk, NE);
  for (int i = s + tid; i < e; i += 256) {
    int r = row[i];
    if (r < num_owned) {
      int p = atomicAdd(&cur[r >> 6], 1);
      pairs[p] = ((uint32)col[i] << 6) | (uint32)(r & 63);
    }
  }
}

// ---------------- fused aggregate: one block per 64-node bucket, LDS f32 accumulators
__global__ __launch_bounds__(256)
void aggB_kernel(const uint32* __restrict__ hb32, const uint32* __restrict__ pairs,
                 const int* __restrict__ bstart, const float* __restrict__ dis,
                 const float* __restrict__ bias, float* __restrict__ out,
                 int num_owned, int n_scan) {
  __shared__ float acc[64][128];    // 32 KB
  const int tid = threadIdx.x;
  const int b = blockIdx.x;
  for (int i = tid; i < 64 * 32; i += 256)
    *(float4*)&((float*)acc)[i * 4] = make_float4(0.f, 0.f, 0.f, 0.f);
  __syncthreads();

  const int bs = bstart[b * NSB];
  const int be = bstart[min((b + 1) * NSB, n_scan)];
  const int lane = tid & 63;
  const int w = tid >> 6;

  for (int e = bs + w; e < be; e += 4) {
    uint32 p = pairs[e];
    int src = (int)(p >> 6);
    int nl = (int)(p & 63u);
    uint32 v = hb32[src * 64 + lane];
    atomicAdd(&acc[nl][lane * 2 + 0], bf2f((unsigned short)(v & 0xffff)));
    atomicAdd(&acc[nl][lane * 2 + 1], bf2f((unsigned short)(v >> 16)));
  }
  __syncthreads();

  const int n0 = b * 64;
  for (int i = tid; i < 64 * 32; i += 256) {
    int nl = i >> 5;
    int c4 = (i & 31) * 4;
    int node = n0 + nl;
    if (node < num_owned) {
      float d = dis[node];
      float4 a = *(float4*)&acc[nl][c4];
      float4 bb = *(const float4*)&bias[c4];
      float4 o;
      o.x = a.x * d + bb.x;
      o.y = a.y * d + bb.y;
      o.z = a.z * d + bb.z;
      o.w = a.w * d + bb.w;
      *(float4*)&out[(size_t)node * 128 + c4] = o;
    }
  }
}

extern "C" void kernel_launch(void* const* d_in, const int* in_sizes, int n_in,
                              void* d_out, int out_size, void* d_ws, size_t ws_size,
                              hipStream_t stream) {
  const float* x    = (const float*)d_in[0];
  const float* w    = (const float*)d_in[1];
  const float* bias = (const float*)d_in[2];
  const float* dis  = (const float*)d_in[3];
  const int*   row  = (const int*)d_in[4];
  const int*   col  = (const int*)d_in[5];

  const int OC = in_sizes[2];            // 128
  const int IC = in_sizes[1] / OC;       // 128
  const int NL = in_sizes[0] / IC;       // 100000
  const int NE = in_sizes[4];            // 1600000
  const int num_owned = out_size / OC;   // 80000
  float* out = (float*)d_out;

  const int NB = (num_owned + 63) >> 6;              // 1250 buckets of 64 nodes
  const int n_scan = NB * NSB;                       // 320000
  // chunk: multiple of 256, identical partition for bhist & scatter
  const int chunk = (((NE + NSB - 1) / NSB) + 255) & ~255;

  char* ws = (char*)d_ws;
  size_t off = 0;
  auto alloc = [&](size_t bytes) -> void* {
    void* p = ws + off;
    off += (bytes + 255) & ~(size_t)255;
    return p;
  };
  unsigned short* hb  = (unsigned short*)alloc((size_t)NL * OC * sizeof(unsigned short));
  int*    bcnt   = (int*)alloc((size_t)n_scan * sizeof(int));
  int*    bstart = (int*)alloc(((size_t)n_scan + 1) * sizeof(int));
  int*    bsum   = (int*)alloc((size_t)((n_scan + 255) / 256) * sizeof(int));
  int*    bsum2  = (int*)alloc((size_t)((n_scan + 255) / 256) * sizeof(int));
  uint32* pairs  = (uint32*)alloc((size_t)NE * sizeof(uint32));
  (void)ws_size; (void)n_in;

  gemm_scale_kernel<<<(NL + 63) / 64, 256, 0, stream>>>(x, w, dis, hb, NL);

  bhist_kernel<<<NSB, 256, 0, stream>>>(row, bcnt, NE, num_owned, NB, chunk);

  int nb = (n_scan + 255) / 256;                     // 1250
  scan_block_kernel<<<nb, 256, 0, stream>>>(bcnt, bstart, bsum, n_scan);
  scan_top_kernel<<<1, 512, 0, stream>>>(bsum, bsum2, nb);
  add_off_kernel<<<nb, 256, 0, stream>>>(bstart, bsum2, bcnt, n_scan);

  scatter_kernel<<<NSB, 256, 0, stream>>>(row, col, bstart, pairs, NE, num_owned, NB, chunk);

  aggB_kernel<<<NB, 256, 0, stream>>>((const uint32*)hb, pairs, bstart, dis, bias, out,
                                      num_owned, n_scan);
}

// Round 6
// 164.525 us; speedup vs baseline: 5.7722x; 5.7722x over previous
//
#include <hip/hip_runtime.h>

typedef unsigned int uint32;

#define NSB 256          // hist/scatter blocks
#define MAXNB 1280       // LDS bucket counters capacity (NB = ceil(num_owned/64))

__device__ __forceinline__ unsigned short f2bf(float f) {
  uint32 b = __float_as_uint(f);
  uint32 r = (b + 0x7fffu + ((b >> 16) & 1u)) >> 16;   // round-to-nearest-even
  return (unsigned short)r;
}
__device__ __forceinline__ float bf2f(unsigned short u) {
  return __uint_as_float(((uint32)u) << 16);
}

// ---------------- GEMM with deg scaling: h[r][c] = dis[r] * sum_k x[r][k]*w[k][c]
__global__ __launch_bounds__(256)
void gemm_scale_kernel(const float* __restrict__ x, const float* __restrict__ w,
                       const float* __restrict__ dis, unsigned short* __restrict__ hb, int NL) {
  const int IC = 128, OC = 128, BK = 32;
  __shared__ float xs[64][BK + 4];
  __shared__ float ws[BK][OC];
  const int tid = threadIdx.x;
  const int tx = tid & 31;
  const int ty = tid >> 5;
  const int row0 = blockIdx.x * 64;
  float acc[8][4] = {};

  for (int kc = 0; kc < IC; kc += BK) {
#pragma unroll
    for (int i = 0; i < 2; ++i) {
      int idx = i * 256 + tid;
      int r = idx >> 3, c4 = idx & 7;
      float4 v = make_float4(0.f, 0.f, 0.f, 0.f);
      int gr = row0 + r;
      if (gr < NL) v = *(const float4*)&x[(size_t)gr * IC + kc + c4 * 4];
      *(float4*)&xs[r][c4 * 4] = v;
    }
#pragma unroll
    for (int i = 0; i < 4; ++i) {
      int idx = i * 256 + tid;
      int r = idx >> 5, c4 = idx & 31;
      *(float4*)&ws[r][c4 * 4] = *(const float4*)&w[(size_t)(kc + r) * OC + c4 * 4];
    }
    __syncthreads();
#pragma unroll
    for (int k = 0; k < BK; ++k) {
      float4 wv = *(const float4*)&ws[k][tx * 4];
#pragma unroll
      for (int i = 0; i < 8; ++i) {
        float xv = xs[ty * 8 + i][k];
        acc[i][0] += xv * wv.x;
        acc[i][1] += xv * wv.y;
        acc[i][2] += xv * wv.z;
        acc[i][3] += xv * wv.w;
      }
    }
    __syncthreads();
  }
#pragma unroll
  for (int i = 0; i < 8; ++i) {
    int r = row0 + ty * 8 + i;
    if (r < NL) {
      float d = dis[r];
      ushort4 o;
      o.x = f2bf(acc[i][0] * d);
      o.y = f2bf(acc[i][1] * d);
      o.z = f2bf(acc[i][2] * d);
      o.w = f2bf(acc[i][3] * d);
      *(ushort4*)&hb[(size_t)r * OC + tx * 4] = o;
    }
  }
}

// ---------------- per-block bucket histogram (bucket = dst>>6), LDS-privatized
__global__ __launch_bounds__(256)
void bhist_kernel(const int* __restrict__ row, int* __restrict__ bcnt,
                  int NE, int num_owned, int NB, int chunk) {
  __shared__ int h[MAXNB];
  const int tid = threadIdx.x;
  const int blk = blockIdx.x;
  for (int b = tid; b < NB; b += 256) h[b] = 0;
  __syncthreads();
  int s = blk * chunk;
  int e = min(s + chunk, NE);
  for (int i = s + tid; i < e; i += 256) {
    int r = row[i];
    if (r < num_owned) atomicAdd(&h[r >> 6], 1);
  }
  __syncthreads();
  for (int b = tid; b < NB; b += 256) bcnt[b * NSB + blk] = h[b];
}

// ---------------- 2-level exclusive scan over n = NB*NSB counts
__global__ __launch_bounds__(256)
void scan_block_kernel(const int* __restrict__ counts, int* __restrict__ offsets,
                       int* __restrict__ bsum, int n) {
  __shared__ int lds[256];
  int tid = threadIdx.x;
  int i = blockIdx.x * 256 + tid;
  int v = (i < n) ? counts[i] : 0;
  lds[tid] = v;
  __syncthreads();
#pragma unroll
  for (int off = 1; off < 256; off <<= 1) {
    int t = (tid >= off) ? lds[tid - off] : 0;
    __syncthreads();
    lds[tid] += t;
    __syncthreads();
  }
  if (i < n) offsets[i] = lds[tid] - v;
  if (tid == 255) bsum[blockIdx.x] = lds[255];
}

// single-block looping scan over nb block sums
__global__ __launch_bounds__(512)
void scan_top_kernel(const int* __restrict__ bsum, int* __restrict__ bsum2, int nb) {
  __shared__ int lds[512];
  __shared__ int carry;
  int tid = threadIdx.x;
  if (tid == 0) carry = 0;
  __syncthreads();
  for (int base = 0; base < nb; base += 512) {
    int idx = base + tid;
    int v = (idx < nb) ? bsum[idx] : 0;
    lds[tid] = v;
    __syncthreads();
    for (int off = 1; off < 512; off <<= 1) {
      int t = (tid >= off) ? lds[tid - off] : 0;
      __syncthreads();
      lds[tid] += t;
      __syncthreads();
    }
    if (idx < nb) bsum2[idx] = carry + lds[tid] - v;
    __syncthreads();
    if (tid == 0) carry += lds[511];
    __syncthreads();
  }
}

// add block offsets; write grand total at offsets[n]
__global__ __launch_bounds__(256)
void add_off_kernel(int* __restrict__ offsets, const int* __restrict__ bsum2,
                    const int* __restrict__ counts, int n) {
  int i = blockIdx.x * 256 + threadIdx.x;
  if (i < n) {
    int o = offsets[i] + bsum2[blockIdx.x];
    offsets[i] = o;
    if (i == n - 1) offsets[n] = o + counts[i];
  }
}

// ---------------- scatter edges into bucket-ordered packed array (block-private runs)
__global__ __launch_bounds__(256)
void scatter_kernel(const int* __restrict__ row, const int* __restrict__ col,
                    const int* __restrict__ bstart, uint32* __restrict__ pairs,
                    int NE, int num_owned, int NB, int chunk) {
  __shared__ int cur[MAXNB];
  const int tid = threadIdx.x;
  const int blk = blockIdx.x;
  for (int b = tid; b < NB; b += 256) cur[b] = bstart[b * NSB + blk];
  __syncthreads();
  int s = blk * chunk;
  int e = min(s + chunk, NE);
  for (int i = s + tid; i < e; i += 256) {
    int r = row[i];
    if (r < num_owned) {
      int p = atomicAdd(&cur[r >> 6], 1);
      pairs[p] = ((uint32)col[i] << 6) | (uint32)(r & 63);
    }
  }
}

// ---------------- per-bucket counting sort -> node-contiguous CSR + nstart/nend
__global__ __launch_bounds__(256)
void bsort_kernel(const uint32* __restrict__ pairs, const int* __restrict__ bstart,
                  int* __restrict__ csr, int* __restrict__ nstart, int* __restrict__ nend,
                  int num_owned, int n_scan) {
  __shared__ int h[64];
  __shared__ int offs[64];
  __shared__ int cur[64];
  const int tid = threadIdx.x;
  const int b = blockIdx.x;
  if (tid < 64) { h[tid] = 0; cur[tid] = 0; }
  __syncthreads();
  const int bs = bstart[b * NSB];
  const int be = bstart[min((b + 1) * NSB, n_scan)];
  for (int e = bs + tid; e < be; e += 256)
    atomicAdd(&h[pairs[e] & 63u], 1);
  __syncthreads();
  if (tid < 64) {                       // wave-0 exclusive scan over 64 counts
    int v = h[tid];
    int s = v;
#pragma unroll
    for (int off = 1; off < 64; off <<= 1) {
      int t = __shfl_up(s, off, 64);
      if (tid >= off) s += t;
    }
    offs[tid] = s - v;
    int node = b * 64 + tid;
    if (node < num_owned) {
      nstart[node] = bs + s - v;
      nend[node]   = bs + s;
    }
  }
  __syncthreads();
  for (int e = bs + tid; e < be; e += 256) {
    uint32 p = pairs[e];
    int nl = (int)(p & 63u);
    int pos = atomicAdd(&cur[nl], 1);
    csr[bs + offs[nl] + pos] = (int)(p >> 6);
  }
}

// ---------------- gather-sum aggregate: one wave per owned node, lane owns 2 bf16 cols
__global__ __launch_bounds__(256)
void agg_kernel(const unsigned short* __restrict__ hb, const int* __restrict__ csr_col,
                const int* __restrict__ nstart, const int* __restrict__ nend,
                const float* __restrict__ dis, const float* __restrict__ bias,
                float* __restrict__ out, int num_owned) {
  int node = blockIdx.x * 4 + (threadIdx.x >> 6);
  int lane = threadIdx.x & 63;
  if (node >= num_owned) return;
  int e = nstart[node];
  int endv = nend[node];
  int c0 = lane * 2;
  float ax = 0.f, ay = 0.f;
  for (; e + 8 <= endv; e += 8) {
    int s[8];
#pragma unroll
    for (int j = 0; j < 8; ++j) s[j] = csr_col[e + j];
    uint32 v[8];
#pragma unroll
    for (int j = 0; j < 8; ++j) v[j] = *(const uint32*)&hb[(size_t)s[j] * 128 + c0];
#pragma unroll
    for (int j = 0; j < 8; ++j) {
      ax += bf2f((unsigned short)(v[j] & 0xffff));
      ay += bf2f((unsigned short)(v[j] >> 16));
    }
  }
  for (; e < endv; ++e) {
    int s = csr_col[e];
    uint32 v = *(const uint32*)&hb[(size_t)s * 128 + c0];
    ax += bf2f((unsigned short)(v & 0xffff));
    ay += bf2f((unsigned short)(v >> 16));
  }
  float d = dis[node];
  float2 b = *(const float2*)&bias[c0];
  float2 o;
  o.x = ax * d + b.x;
  o.y = ay * d + b.y;
  *(float2*)&out[(size_t)node * 128 + c0] = o;
}

extern "C" void kernel_launch(void* const* d_in, const int* in_sizes, int n_in,
                              void* d_out, int out_size, void* d_ws, size_t ws_size,
                              hipStream_t stream) {
  const float* x    = (const float*)d_in[0];
  const float* w    = (const float*)d_in[1];
  const float* bias = (const float*)d_in[2];
  const float* dis  = (const float*)d_in[3];
  const int*   row  = (const int*)d_in[4];
  const int*   col  = (const int*)d_in[5];

  const int OC = in_sizes[2];            // 128
  const int IC = in_sizes[1] / OC;       // 128
  const int NL = in_sizes[0] / IC;       // 100000
  const int NE = in_sizes[4];            // 1600000
  const int num_owned = out_size / OC;   // 80000
  float* out = (float*)d_out;

  const int NB = (num_owned + 63) >> 6;              // 1250 buckets of 64 nodes
  const int n_scan = NB * NSB;                       // 320000
  const int chunk = (((NE + NSB - 1) / NSB) + 255) & ~255;

  char* ws = (char*)d_ws;
  size_t off = 0;
  auto alloc = [&](size_t bytes) -> void* {
    void* p = ws + off;
    off += (bytes + 255) & ~(size_t)255;
    return p;
  };
  unsigned short* hb  = (unsigned short*)alloc((size_t)NL * OC * sizeof(unsigned short));
  int*    bcnt   = (int*)alloc((size_t)n_scan * sizeof(int));
  int*    bstart = (int*)alloc(((size_t)n_scan + 1) * sizeof(int));
  int*    bsum   = (int*)alloc((size_t)((n_scan + 255) / 256) * sizeof(int));
  int*    bsum2  = (int*)alloc((size_t)((n_scan + 255) / 256) * sizeof(int));
  uint32* pairs  = (uint32*)alloc((size_t)NE * sizeof(uint32));
  int*    csr    = (int*)alloc((size_t)NE * sizeof(int));
  int*    nstart = (int*)alloc((size_t)num_owned * sizeof(int));
  int*    nend   = (int*)alloc((size_t)num_owned * sizeof(int));
  (void)ws_size; (void)n_in;

  gemm_scale_kernel<<<(NL + 63) / 64, 256, 0, stream>>>(x, w, dis, hb, NL);

  bhist_kernel<<<NSB, 256, 0, stream>>>(row, bcnt, NE, num_owned, NB, chunk);

  int nb = (n_scan + 255) / 256;                     // 1250
  scan_block_kernel<<<nb, 256, 0, stream>>>(bcnt, bstart, bsum, n_scan);
  scan_top_kernel<<<1, 512, 0, stream>>>(bsum, bsum2, nb);
  add_off_kernel<<<nb, 256, 0, stream>>>(bstart, bsum2, bcnt, n_scan);

  scatter_kernel<<<NSB, 256, 0, stream>>>(row, col, bstart, pairs, NE, num_owned, NB, chunk);
  bsort_kernel<<<NB, 256, 0, stream>>>(pairs, bstart, csr, nstart, nend, num_owned, n_scan);

  agg_kernel<<<(num_owned + 3) / 4, 256, 0, stream>>>(hb, csr, nstart, nend, dis, bias, out, num_owned);
}

// Round 7
// 139.365 us; speedup vs baseline: 6.8143x; 1.1805x over previous
//
#include <hip/hip_runtime.h>

typedef unsigned int uint32;
typedef short bf16x8 __attribute__((ext_vector_type(8)));
typedef float f32x4 __attribute__((ext_vector_type(4)));

#define NSB 256          // hist/scatter blocks
#define MAXNB 1280       // LDS bucket counters capacity (NB = ceil(num_owned/64))

__device__ __forceinline__ unsigned short f2bf(float f) {
  uint32 b = __float_as_uint(f);
  uint32 r = (b + 0x7fffu + ((b >> 16) & 1u)) >> 16;   // round-to-nearest-even
  return (unsigned short)r;
}
__device__ __forceinline__ float bf2f(unsigned short u) {
  return __uint_as_float(((uint32)u) << 16);
}

// ---------------- one-time: W[k][c] fp32 -> wt[c][k] bf16
__global__ __launch_bounds__(256)
void prep_w_kernel(const float* __restrict__ w, short* __restrict__ wtb) {
  int i = blockIdx.x * 256 + threadIdx.x;
  if (i < 128 * 128) {
    int c = i >> 7, k = i & 127;
    wtb[c * 128 + k] = (short)f2bf(w[(size_t)k * 128 + c]);
  }
}

// ---------------- MFMA GEMM: hb[r][c] = bf16( dis[r] * sum_k x[r][k]*w[k][c] )
// block 256 (4 waves); tile 128 rows x 128 cols; wave: 32 rows x 128 cols.
__global__ __launch_bounds__(256)
void gemm_mfma_kernel(const float* __restrict__ x, const short* __restrict__ wtb,
                      const float* __restrict__ dis, unsigned short* __restrict__ hb, int NL) {
  __shared__ short As[128 * 72];    // [row][k in 64-half], pad 72 (16B-aligned rows)
  __shared__ short Bt[128 * 136];   // [col][k 0..127], pad 136
  const int tid  = threadIdx.x;
  const int lane = tid & 63;
  const int wid  = tid >> 6;
  const int li   = lane & 15;
  const int lh   = lane >> 4;       // 0..3
  const int row0 = blockIdx.x * 128;

  // stage Bt (bf16 [col][128]) -> LDS padded
  {
    const uint4* src = (const uint4*)wtb;      // 2048 x 16B
    for (int u = tid; u < 2048; u += 256) {
      int c = u >> 4, j = u & 15;
      *(uint4*)&Bt[c * 136 + j * 8] = src[u];
    }
  }

  f32x4 acc[2][8] = {};

  for (int kh = 0; kh < 2; ++kh) {
    __syncthreads();
    // stage As: 128 rows x 64 k (fp32 -> bf16), 2 threads per row
    {
      int r = tid >> 1, kp = (tid & 1) * 32;
      int gr = row0 + r;
      const float* xs = &x[(size_t)gr * 128 + kh * 64 + kp];
#pragma unroll
      for (int q = 0; q < 8; ++q) {
        float4 v = (gr < NL) ? *(const float4*)&xs[q * 4] : make_float4(0.f, 0.f, 0.f, 0.f);
        ushort4 o;
        o.x = f2bf(v.x); o.y = f2bf(v.y); o.z = f2bf(v.z); o.w = f2bf(v.w);
        *(ushort4*)&As[r * 72 + kp + q * 4] = o;
      }
    }
    __syncthreads();
#pragma unroll
    for (int c = 0; c < 2; ++c) {
      int kk  = c * 32 + lh * 8;                 // k within the staged half
      int kkg = kh * 64 + kk;                    // global k (for Bt)
      bf16x8 af[2], bfr[8];
#pragma unroll
      for (int rf = 0; rf < 2; ++rf)
        af[rf] = *(const bf16x8*)&As[(wid * 32 + rf * 16 + li) * 72 + kk];
#pragma unroll
      for (int cf = 0; cf < 8; ++cf)
        bfr[cf] = *(const bf16x8*)&Bt[(cf * 16 + li) * 136 + kkg];
#pragma unroll
      for (int rf = 0; rf < 2; ++rf)
#pragma unroll
        for (int cf = 0; cf < 8; ++cf)
          acc[rf][cf] = __builtin_amdgcn_mfma_f32_16x16x32_bf16(af[rf], bfr[cf], acc[rf][cf], 0, 0, 0);
    }
  }

  // epilogue: C/D layout col=lane&15, row=(lane>>4)*4+reg
#pragma unroll
  for (int rf = 0; rf < 2; ++rf) {
#pragma unroll
    for (int j = 0; j < 4; ++j) {
      int r = row0 + wid * 32 + rf * 16 + lh * 4 + j;
      if (r < NL) {
        float d = dis[r];
        size_t base = (size_t)r * 128 + li;
#pragma unroll
        for (int cf = 0; cf < 8; ++cf)
          hb[base + cf * 16] = f2bf(acc[rf][cf][j] * d);
      }
    }
  }
}

// ---------------- per-block bucket histogram (bucket = dst>>6), LDS-privatized
__global__ __launch_bounds__(256)
void bhist_kernel(const int* __restrict__ row, int* __restrict__ bcnt,
                  int NE, int num_owned, int NB, int chunk) {
  __shared__ int h[MAXNB];
  const int tid = threadIdx.x;
  const int blk = blockIdx.x;
  for (int b = tid; b < NB; b += 256) h[b] = 0;
  __syncthreads();
  int s = blk * chunk;
  int e = min(s + chunk, NE);
  for (int i = s + tid; i < e; i += 256) {
    int r = row[i];
    if (r < num_owned) atomicAdd(&h[r >> 6], 1);
  }
  __syncthreads();
  for (int b = tid; b < NB; b += 256) bcnt[b * NSB + blk] = h[b];
}

// ---------------- 2-level exclusive scan over n = NB*NSB counts
__global__ __launch_bounds__(256)
void scan_block_kernel(const int* __restrict__ counts, int* __restrict__ offsets,
                       int* __restrict__ bsum, int n) {
  __shared__ int lds[256];
  int tid = threadIdx.x;
  int i = blockIdx.x * 256 + tid;
  int v = (i < n) ? counts[i] : 0;
  lds[tid] = v;
  __syncthreads();
#pragma unroll
  for (int off = 1; off < 256; off <<= 1) {
    int t = (tid >= off) ? lds[tid - off] : 0;
    __syncthreads();
    lds[tid] += t;
    __syncthreads();
  }
  if (i < n) offsets[i] = lds[tid] - v;
  if (tid == 255) bsum[blockIdx.x] = lds[255];
}

__global__ __launch_bounds__(512)
void scan_top_kernel(const int* __restrict__ bsum, int* __restrict__ bsum2, int nb) {
  __shared__ int lds[512];
  __shared__ int carry;
  int tid = threadIdx.x;
  if (tid == 0) carry = 0;
  __syncthreads();
  for (int base = 0; base < nb; base += 512) {
    int idx = base + tid;
    int v = (idx < nb) ? bsum[idx] : 0;
    lds[tid] = v;
    __syncthreads();
    for (int off = 1; off < 512; off <<= 1) {
      int t = (tid >= off) ? lds[tid - off] : 0;
      __syncthreads();
      lds[tid] += t;
      __syncthreads();
    }
    if (idx < nb) bsum2[idx] = carry + lds[tid] - v;
    __syncthreads();
    if (tid == 0) carry += lds[511];
    __syncthreads();
  }
}

__global__ __launch_bounds__(256)
void add_off_kernel(int* __restrict__ offsets, const int* __restrict__ bsum2,
                    const int* __restrict__ counts, int n) {
  int i = blockIdx.x * 256 + threadIdx.x;
  if (i < n) {
    int o = offsets[i] + bsum2[blockIdx.x];
    offsets[i] = o;
    if (i == n - 1) offsets[n] = o + counts[i];
  }
}

// ---------------- scatter edges into bucket-ordered packed array (block-private runs)
__global__ __launch_bounds__(256)
void scatter_kernel(const int* __restrict__ row, const int* __restrict__ col,
                    const int* __restrict__ bstart, uint32* __restrict__ pairs,
                    int NE, int num_owned, int NB, int chunk) {
  __shared__ int cur[MAXNB];
  const int tid = threadIdx.x;
  const int blk = blockIdx.x;
  for (int b = tid; b < NB; b += 256) cur[b] = bstart[b * NSB + blk];
  __syncthreads();
  int s = blk * chunk;
  int e = min(s + chunk, NE);
  for (int i = s + tid; i < e; i += 256) {
    int r = row[i];
    if (r < num_owned) {
      int p = atomicAdd(&cur[r >> 6], 1);
      pairs[p] = ((uint32)col[i] << 6) | (uint32)(r & 63);
    }
  }
}

// ---------------- per-bucket counting sort -> node-contiguous CSR + nstart/nend
__global__ __launch_bounds__(256)
void bsort_kernel(const uint32* __restrict__ pairs, const int* __restrict__ bstart,
                  int* __restrict__ csr, int* __restrict__ nstart, int* __restrict__ nend,
                  int num_owned, int n_scan) {
  __shared__ int h[64];
  __shared__ int offs[64];
  __shared__ int cur[64];
  const int tid = threadIdx.x;
  const int b = blockIdx.x;
  if (tid < 64) { h[tid] = 0; cur[tid] = 0; }
  __syncthreads();
  const int bs = bstart[b * NSB];
  const int be = bstart[min((b + 1) * NSB, n_scan)];
  for (int e = bs + tid; e < be; e += 256)
    atomicAdd(&h[pairs[e] & 63u], 1);
  __syncthreads();
  if (tid < 64) {
    int v = h[tid];
    int s = v;
#pragma unroll
    for (int off = 1; off < 64; off <<= 1) {
      int t = __shfl_up(s, off, 64);
      if (tid >= off) s += t;
    }
    offs[tid] = s - v;
    int node = b * 64 + tid;
    if (node < num_owned) {
      nstart[node] = bs + s - v;
      nend[node]   = bs + s;
    }
  }
  __syncthreads();
  for (int e = bs + tid; e < be; e += 256) {
    uint32 p = pairs[e];
    int nl = (int)(p & 63u);
    int pos = atomicAdd(&cur[nl], 1);
    csr[bs + offs[nl] + pos] = (int)(p >> 6);
  }
}

// ---------------- aggregate: one wave per node; 4x16-lane groups, dwordx4 gathers
__global__ __launch_bounds__(256)
void agg_kernel(const unsigned short* __restrict__ hb, const int* __restrict__ csr,
                const int* __restrict__ nstart, const int* __restrict__ nend,
                const float* __restrict__ dis, const float* __restrict__ bias,
                float* __restrict__ out, int num_owned) {
  int node = blockIdx.x * 4 + (threadIdx.x >> 6);
  int lane = threadIdx.x & 63;
  if (node >= num_owned) return;
  const int g  = lane >> 4;         // edge subgroup 0..3
  const int i8 = (lane & 15) * 8;   // col base (8 bf16 = 16B)
  int ns = nstart[node], ne = nend[node];
  float a[8] = {};

  auto acc16 = [&](uint4 v) {
    a[0] += bf2f((unsigned short)(v.x & 0xffff));
    a[1] += bf2f((unsigned short)(v.x >> 16));
    a[2] += bf2f((unsigned short)(v.y & 0xffff));
    a[3] += bf2f((unsigned short)(v.y >> 16));
    a[4] += bf2f((unsigned short)(v.z & 0xffff));
    a[5] += bf2f((unsigned short)(v.z >> 16));
    a[6] += bf2f((unsigned short)(v.w & 0xffff));
    a[7] += bf2f((unsigned short)(v.w >> 16));
  };

  int e = ns + g;
  for (; e + 12 < ne; e += 16) {      // 16 edges per wave-iter (4 per group)
    int s0 = csr[e], s1 = csr[e + 4], s2 = csr[e + 8], s3 = csr[e + 12];
    uint4 v0 = *(const uint4*)&hb[(size_t)s0 * 128 + i8];
    uint4 v1 = *(const uint4*)&hb[(size_t)s1 * 128 + i8];
    uint4 v2 = *(const uint4*)&hb[(size_t)s2 * 128 + i8];
    uint4 v3 = *(const uint4*)&hb[(size_t)s3 * 128 + i8];
    acc16(v0); acc16(v1); acc16(v2); acc16(v3);
  }
  for (; e < ne; e += 4) {
    int s = csr[e];
    uint4 v = *(const uint4*)&hb[(size_t)s * 128 + i8];
    acc16(v);
  }

#pragma unroll
  for (int k = 0; k < 8; ++k) {
    a[k] += __shfl_xor(a[k], 16, 64);
    a[k] += __shfl_xor(a[k], 32, 64);
  }
  if (g == 0) {
    float d = dis[node];
    float4 b0 = *(const float4*)&bias[i8];
    float4 b1 = *(const float4*)&bias[i8 + 4];
    float4 o0, o1;
    o0.x = a[0] * d + b0.x; o0.y = a[1] * d + b0.y;
    o0.z = a[2] * d + b0.z; o0.w = a[3] * d + b0.w;
    o1.x = a[4] * d + b1.x; o1.y = a[5] * d + b1.y;
    o1.z = a[6] * d + b1.z; o1.w = a[7] * d + b1.w;
    *(float4*)&out[(size_t)node * 128 + i8] = o0;
    *(float4*)&out[(size_t)node * 128 + i8 + 4] = o1;
  }
}

extern "C" void kernel_launch(void* const* d_in, const int* in_sizes, int n_in,
                              void* d_out, int out_size, void* d_ws, size_t ws_size,
                              hipStream_t stream) {
  const float* x    = (const float*)d_in[0];
  const float* w    = (const float*)d_in[1];
  const float* bias = (const float*)d_in[2];
  const float* dis  = (const float*)d_in[3];
  const int*   row  = (const int*)d_in[4];
  const int*   col  = (const int*)d_in[5];

  const int OC = in_sizes[2];            // 128
  const int IC = in_sizes[1] / OC;       // 128
  const int NL = in_sizes[0] / IC;       // 100000
  const int NE = in_sizes[4];            // 1600000
  const int num_owned = out_size / OC;   // 80000
  float* out = (float*)d_out;

  const int NB = (num_owned + 63) >> 6;              // 1250 buckets of 64 nodes
  const int n_scan = NB * NSB;                       // 320000
  const int chunk = (((NE + NSB - 1) / NSB) + 255) & ~255;

  char* ws = (char*)d_ws;
  size_t off = 0;
  auto alloc = [&](size_t bytes) -> void* {
    void* p = ws + off;
    off += (bytes + 255) & ~(size_t)255;
    return p;
  };
  unsigned short* hb  = (unsigned short*)alloc((size_t)NL * OC * sizeof(unsigned short));
  short*  wtb    = (short*)alloc((size_t)IC * OC * sizeof(short));
  int*    bcnt   = (int*)alloc((size_t)n_scan * sizeof(int));
  int*    bstart = (int*)alloc(((size_t)n_scan + 1) * sizeof(int));
  int*    bsum   = (int*)alloc((size_t)((n_scan + 255) / 256) * sizeof(int));
  int*    bsum2  = (int*)alloc((size_t)((n_scan + 255) / 256) * sizeof(int));
  uint32* pairs  = (uint32*)alloc((size_t)NE * sizeof(uint32));
  int*    csr    = (int*)alloc((size_t)NE * sizeof(int));
  int*    nstart = (int*)alloc((size_t)num_owned * sizeof(int));
  int*    nend   = (int*)alloc((size_t)num_owned * sizeof(int));
  (void)ws_size; (void)n_in;

  prep_w_kernel<<<64, 256, 0, stream>>>(w, wtb);
  gemm_mfma_kernel<<<(NL + 127) / 128, 256, 0, stream>>>(x, wtb, dis, hb, NL);

  bhist_kernel<<<NSB, 256, 0, stream>>>(row, bcnt, NE, num_owned, NB, chunk);

  int nb = (n_scan + 255) / 256;                     // 1250
  scan_block_kernel<<<nb, 256, 0, stream>>>(bcnt, bstart, bsum, n_scan);
  scan_top_kernel<<<1, 512, 0, stream>>>(bsum, bsum2, nb);
  add_off_kernel<<<nb, 256, 0, stream>>>(bstart, bsum2, bcnt, n_scan);

  scatter_kernel<<<NSB, 256, 0, stream>>>(row, col, bstart, pairs, NE, num_owned, NB, chunk);
  bsort_kernel<<<NB, 256, 0, stream>>>(pairs, bstart, csr, nstart, nend, num_owned, n_scan);

  agg_kernel<<<(num_owned + 3) / 4, 256, 0, stream>>>(hb, csr, nstart, nend, dis, bias, out, num_owned);
}